// Round 11
// baseline (3375.024 us; speedup 1.0000x reference)
//
#include <hip/hip_runtime.h>

typedef unsigned int u32;
typedef unsigned short u16;
typedef _Float16 half8 __attribute__((ext_vector_type(8)));
typedef float f32x4 __attribute__((ext_vector_type(4)));
typedef _Float16 h2t __attribute__((ext_vector_type(2)));

union H2U { u32 u; h2t h; u16 s[2]; };
union U128 { uint4 u; half8 h; };

#if defined(__has_builtin)
#if __has_builtin(__builtin_amdgcn_fdot2)
#define HAS_FDOT2 1
#endif
#endif

__device__ __forceinline__ float dot2f(u32 w, u32 x, float acc){
  H2U a, b; a.u = w; b.u = x;
#ifdef HAS_FDOT2
  return __builtin_amdgcn_fdot2(a.h, b.h, acc, false);
#else
  return acc + (float)a.h.x * (float)b.h.x + (float)a.h.y * (float)b.h.y;
#endif
}
__device__ __forceinline__ u32 packh2(float a, float b){
  H2U u; u.h.x = (_Float16)a; u.h.y = (_Float16)b; return u.u;
}
__device__ __forceinline__ u16 f16b(float x){
  union { _Float16 h; u16 u; } c; c.h = (_Float16)x; return c.u;
}
__device__ __forceinline__ float rcpf(float x){ return __builtin_amdgcn_rcpf(x); }
__device__ __forceinline__ float sigm(float x){ return rcpf(1.0f + __expf(-x)); }
__device__ __forceinline__ float sigm_slow(float x){ return 1.0f/(1.0f + __expf(-x)); }
__device__ __forceinline__ float tanh_f(float x){
  return fmaf(-2.0f, rcpf(1.0f + __expf(2.0f*x)), 1.0f);
}
__device__ __forceinline__ half8 pack8(float4 u, float4 v){
  half8 r;
  r[0]=(_Float16)u.x; r[1]=(_Float16)u.y; r[2]=(_Float16)u.z; r[3]=(_Float16)u.w;
  r[4]=(_Float16)v.x; r[5]=(_Float16)v.y; r[6]=(_Float16)v.z; r[7]=(_Float16)v.w;
  return r;
}

// Coherence-point access: device-scope sc0 sc1 everywhere — the only sync
// semantics proven on this HW (R4/R7). Asm outputs early-clobber.
#define LDX4_SC(dst, base, off) \
  asm volatile("global_load_dwordx4 %0, %1, off offset:" #off " sc0 sc1" \
               : "=&v"(dst) : "v"(base) : "memory")
#define STSH_SC(base, off, val) \
  asm volatile("global_store_short %0, %1, off offset:" #off " sc0 sc1" \
               :: "v"(base), "v"(val) : "memory")
#define STDW_SC(base, val) \
  asm volatile("global_store_dword %0, %1, off sc0 sc1" \
               :: "v"(base), "v"(val) : "memory")
#define WAIT_VM0() asm volatile("s_waitcnt vmcnt(0)" ::: "memory")

#define T_STEPS 1024
#define NB 64
#define HID 512
#define G3 1536
#define NOBS 64
#define MST 64
#define KIN 128

// ---- ws layout (persistent path), bytes ----
#define OFF_WHHK 0
#define SZ_WHHK (G3*HID*2)                    // 1,572,864
#define OFF_WIHK (OFF_WHHK + SZ_WHHK)
#define SZ_WIHK (G3*KIN*2)                    //   393,216
#define OFF_FCK (OFF_WIHK + SZ_WIHK)
#define SZ_FCK (MST*HID*2)                    //    65,536
#define OFF_FLG (OFF_FCK + SZ_FCK)
#define SZ_FLG (4*32*4)                       //       512 (4 teams x 32 WG flags)
#define OFF_HFULL (OFF_FLG + 4096)
#define SZ_HFULL ((size_t)T_STEPS*NB*HID*2)   // 67,108,864  (h_full[t] = outs[t])
#define WS_NEED (OFF_HFULL + SZ_HFULL)

// ---------------------------------------------------------------------------
// prep2: f32->f16 weight conversion; zero flags with sc0 sc1 stores (the
// persistent kernel polls them via cache-bypass loads). Proven R4/R7.
// ---------------------------------------------------------------------------
__global__ __launch_bounds__(256) void prep2_kernel(
    const float* __restrict__ W_ih, const float* __restrict__ W_hh,
    const float* __restrict__ fc_W, char* __restrict__ ws){
  _Float16* whhk = (_Float16*)(ws + OFF_WHHK);
  _Float16* wihk = (_Float16*)(ws + OFF_WIHK);
  _Float16* fck  = (_Float16*)(ws + OFF_FCK);
  u32* flg       = (u32*)(ws + OFF_FLG);
  long idx = (long)blockIdx.x*256 + threadIdx.x;
  const long N1 = (long)G3*HID, N2 = (long)G3*KIN, N3 = (long)MST*HID;
  const long N4 = SZ_FLG/4;
  if (idx < N1) whhk[idx] = (_Float16)W_hh[idx];
  else if (idx < N1+N2) wihk[idx-N1] = (_Float16)W_ih[idx-N1];
  else if (idx < N1+N2+N3) fck[idx-N1-N2] = (_Float16)fc_W[idx-N1-N2];
  else if (idx < N1+N2+N3+N4) { u32* p = flg + (idx-N1-N2-N3); u32 z = 0; STDW_SC(p, z); }
}

// ---------------------------------------------------------------------------
// X_prior: one WG (1 wave) per batch; F row-resident in VGPRs.
// Writes X_prior into d_out (fc kernel later adds dX in place).
// ---------------------------------------------------------------------------
__global__ __launch_bounds__(64) void xprior_kernel(
    const float* __restrict__ F, const float* __restrict__ x0,
    float* __restrict__ out){
  int b = blockIdx.x, i = threadIdx.x;
  __shared__ float xb[2][64];
  float f[64];
  #pragma unroll
  for (int j=0;j<64;j++) f[j] = F[i*64+j];
  xb[0][i] = x0[b*64+i];
  __syncthreads();
  float* o = out + (size_t)b*1024*64;
  for (int t=0;t<1024;t++){
    int cur = t & 1;
    float a0=0.f,a1=0.f,a2=0.f,a3=0.f;
    #pragma unroll
    for (int j=0;j<64;j+=4){
      a0 = fmaf(f[j+0], xb[cur][j+0], a0);
      a1 = fmaf(f[j+1], xb[cur][j+1], a1);
      a2 = fmaf(f[j+2], xb[cur][j+2], a2);
      a3 = fmaf(f[j+3], xb[cur][j+3], a3);
    }
    float a = (a0+a1)+(a2+a3);
    o[t*64+i] = a;
    xb[cur^1][i] = a;
    __syncthreads();
  }
}

// ---------------------------------------------------------------------------
// Persistent GRU v3.2 — proven R4/R7 flag protocol with the wait narrowed
// to the true dependency set:
//   Consumer wave wv reads h columns [256*wv, 256*wv+256), produced by
//   exactly WGs m' in [16*wv, 16*wv+16). It polls ONLY those 16 flags
//   (strictly weaker wait; the flag->data ordering guarantee per WG is
//   byte-identical to R4/R7: flag tv=t+1 is stored only after that WG's
//   step-t h stores are vmcnt(0)-acked at the coherence point).
// Consequence handled: wave1's own WG flag is no longer in its poll set, so
// wave1 may lead wave0 by one step. part[] is therefore double-buffered by
// t&1. Safety proof: wave1's part-write@t+2 (buffer t&1) requires passing
// syncthreads(t+1); that requires wave0's arrival at syncthreads(t+1),
// which is program-order after wave0's part-read@t (buffer t&1). Hence the
// write never precedes the read it could alias. Writes@t+1 use the other
// buffer. One barrier per iteration, both waves execute it every t.
// Producer side byte-identical to R4/R7.
// ---------------------------------------------------------------------------
__global__ __launch_bounds__(128, 1) void gru_pers3(
    const float* __restrict__ Y, const float* __restrict__ Xp,
    const float* __restrict__ b_ih, const float* __restrict__ b_hh,
    char* __restrict__ ws){
  const _Float16* whhk = (const _Float16*)(ws + OFF_WHHK);
  const _Float16* wihk = (const _Float16*)(ws + OFF_WIHK);
  u32* flags           = (u32*)(ws + OFF_FLG);
  _Float16* h_full     = (_Float16*)(ws + OFF_HFULL);

  const int blk = blockIdx.x;
  const int g = blk >> 5;          // team 0..3
  const int m = blk & 31;          // j-tile 0..31
  const int tid = threadIdx.x;
  const int wv = tid >> 6;         // K-half 0..1
  const int lane = tid & 63;
  const int lr = lane & 15, lk = lane >> 4;
  const int j = m*16 + lr;         // output column (n)

  // Persistent B fragments: 30 x half8 = 120 VGPRs (proven no-spill)
  half8 BhR[8], BhZ[8], BhN[8], BxR[2], BxZ[2], BxN[2];
  #pragma unroll
  for (int c=0;c<8;c++){
    BhR[c] = *(const half8*)(whhk + ((size_t)(       j))*HID + wv*256 + c*32 + lk*8);
    BhZ[c] = *(const half8*)(whhk + ((size_t)(512  + j))*HID + wv*256 + c*32 + lk*8);
    BhN[c] = *(const half8*)(whhk + ((size_t)(1024 + j))*HID + wv*256 + c*32 + lk*8);
  }
  #pragma unroll
  for (int c=0;c<2;c++){
    BxR[c] = *(const half8*)(wihk + ((size_t)(       j))*KIN + wv*64 + c*32 + lk*8);
    BxZ[c] = *(const half8*)(wihk + ((size_t)(512  + j))*KIN + wv*64 + c*32 + lk*8);
    BxN[c] = *(const half8*)(wihk + ((size_t)(1024 + j))*KIN + wv*64 + c*32 + lk*8);
  }

  const float bR  = b_ih[j]      + b_hh[j];
  const float bZ  = b_ih[512+j]  + b_hh[512+j];
  const float bNX = b_ih[1024+j];
  const float bNH = b_hh[1024+j];

  // A-side: wave0 streams Y (k 0..63), wave1 streams Xp (k 64..127);
  // lane row lr = batch within team.
  const float* Arow = (wv==0 ? Y : Xp) + ((size_t)(g*16 + lr))*T_STEPS*64;

  u32* flg = flags + g*32;
  u32* myflag   = flg + m;
  // v3.2: poll ONLY the 16 producers of this wave's K-half columns.
  u32* pollflag = flg + wv*16 + (lane & 15);

  float hold[4] = {0.f, 0.f, 0.f, 0.f};
  __shared__ f32x4 part[2][4][64];   // double-buffered by t&1 (proof above)

  for (int t=0; t<T_STEPS; t++){
    const int s = t & 1;

    // 1) prefetch this wave's input chunk (plain cached loads)
    const float* asrc = Arow + (size_t)t*64;
    float4 i0 = *(const float4*)(asrc + lk*8);
    float4 i1 = *(const float4*)(asrc + lk*8 + 4);
    float4 i2 = *(const float4*)(asrc + 32 + lk*8);
    float4 i3 = *(const float4*)(asrc + 32 + lk*8 + 4);

    // 2) poll: the 16 flags this wave actually depends on (skip at t=0)
    if (t > 0){
      u32 v;
      for(;;){
        asm volatile("global_load_dword %0, %1, off sc0 sc1\n\ts_waitcnt vmcnt(0)"
                     : "=&v"(v) : "v"(pollflag) : "memory");
        if (__all((int)(v >= (u32)t))) break;
      }
    }

    // 3) issue h_t A-frag loads for this wave's K-half (cache-bypass)
    uint4 ah[8];
    if (t > 0){
      const _Float16* hb = h_full + ((size_t)(t-1)*NB + g*16 + lr)*HID + wv*256 + lk*8;
      LDX4_SC(ah[0], hb,   0); LDX4_SC(ah[1], hb,  64);
      LDX4_SC(ah[2], hb, 128); LDX4_SC(ah[3], hb, 192);
      LDX4_SC(ah[4], hb, 256); LDX4_SC(ah[5], hb, 320);
      LDX4_SC(ah[6], hb, 384); LDX4_SC(ah[7], hb, 448);
    }

    // 4a) x-projection MFMAs overlap the h-load round trip (R7-verified)
    f32x4 aR={0,0,0,0}, aZ={0,0,0,0}, aNH={0,0,0,0}, aNX={0,0,0,0};
    {
      half8 A0 = pack8(i0,i1), A1 = pack8(i2,i3);
      aR  = __builtin_amdgcn_mfma_f32_16x16x32_f16(A0, BxR[0], aR, 0,0,0);
      aZ  = __builtin_amdgcn_mfma_f32_16x16x32_f16(A0, BxZ[0], aZ, 0,0,0);
      aNX = __builtin_amdgcn_mfma_f32_16x16x32_f16(A0, BxN[0], aNX,0,0,0);
      aR  = __builtin_amdgcn_mfma_f32_16x16x32_f16(A1, BxR[1], aR, 0,0,0);
      aZ  = __builtin_amdgcn_mfma_f32_16x16x32_f16(A1, BxZ[1], aZ, 0,0,0);
      aNX = __builtin_amdgcn_mfma_f32_16x16x32_f16(A1, BxN[1], aNX,0,0,0);
    }

    // 4b) drain h loads; sched_barrier stops hh-MFMA hoisting past the wait
    WAIT_VM0();
    __builtin_amdgcn_sched_barrier(0);

    // 4c) hh MFMAs
    if (t > 0){
      #pragma unroll
      for (int c=0;c<8;c++){
        U128 u; u.u = ah[c];
        half8 A = u.h;
        aR  = __builtin_amdgcn_mfma_f32_16x16x32_f16(A, BhR[c], aR, 0,0,0);
        aZ  = __builtin_amdgcn_mfma_f32_16x16x32_f16(A, BhZ[c], aZ, 0,0,0);
        aNH = __builtin_amdgcn_mfma_f32_16x16x32_f16(A, BhN[c], aNH,0,0,0);
      }
    }

    // 5) cross-wave K-reduction via LDS (double-buffered; proof in header)
    if (wv == 1){
      part[s][0][lane] = aR;  part[s][1][lane] = aZ;
      part[s][2][lane] = aNH; part[s][3][lane] = aNX;
    }
    __syncthreads();

    if (wv == 0){
      aR  += part[s][0][lane]; aZ  += part[s][1][lane];
      aNH += part[s][2][lane]; aNX += part[s][3][lane];
      // 6) gates in registers: lane owns (batch=lk*4+r, col j)
      float hn[4];
      #pragma unroll
      for (int r=0;r<4;r++){
        float rg = sigm(aR[r] + bR);
        float zg = sigm(aZ[r] + bZ);
        float ng = tanh_f(aNX[r] + bNX + rg*(aNH[r] + bNH));
        hn[r] = (1.f - zg)*ng + zg*hold[r];
        hold[r] = hn[r];
      }
      // 7) publish h_{t+1} into h_full[t]: sc stores -> ack -> flag
      //    (byte-identical to the proven R4/R7 producer)
      _Float16* hw = h_full + ((size_t)t*NB + g*16 + lk*4)*HID + j;
      u32 q0 = (u32)f16b(hn[0]);
      u32 q1 = (u32)f16b(hn[1]);
      u32 q2 = (u32)f16b(hn[2]);
      u32 q3 = (u32)f16b(hn[3]);
      STSH_SC(hw,    0, q0);
      STSH_SC(hw, 1024, q1);
      STSH_SC(hw, 2048, q2);
      STSH_SC(hw, 3072, q3);
      WAIT_VM0();
      if (lane == 0){
        u32 tv = (u32)(t+1);
        STDW_SC(myflag, tv);
      }
    }
  }
}

// ---------------------------------------------------------------------------
// Deferred fc: out = X_prior(d_out) + h_full @ fcW^T + fc_b. MFMA, parallel.
// (h_full written with sc0sc1 at the coherence point; kernel-boundary
// acquire makes fc's plain loads coherent — validated R4/R7.)
// ---------------------------------------------------------------------------
__global__ __launch_bounds__(256) void fc_kernel(
    const float* __restrict__ fc_b, const char* __restrict__ ws,
    float* __restrict__ out){
  const _Float16* fck    = (const _Float16*)(ws + OFF_FCK);
  const _Float16* h_full = (const _Float16*)(ws + OFF_HFULL);
  int blk = blockIdx.x;
  int b  = blk >> 5;
  int t0 = (blk & 31) * 32;
  int tid = threadIdx.x, wv = tid >> 6, lane = tid & 63;
  int lr = lane & 15, lk = lane >> 4;
  int n = wv*16 + lr;
  half8 Bf[16];
  #pragma unroll
  for (int c=0;c<16;c++)
    Bf[c] = *(const half8*)(fck + (size_t)n*HID + c*32 + lk*8);
  float bias = fc_b[n];
  #pragma unroll
  for (int mt=0;mt<2;mt++){
    f32x4 C = {0.f,0.f,0.f,0.f};
    #pragma unroll
    for (int c=0;c<16;c++){
      half8 A = *(const half8*)(h_full + ((size_t)(t0+mt*16+lr)*NB + b)*HID + c*32 + lk*8);
      C = __builtin_amdgcn_mfma_f32_16x16x32_f16(A, Bf[c], C, 0,0,0);
    }
    #pragma unroll
    for (int r=0;r<4;r++){
      int trow = t0 + mt*16 + lk*4 + r;
      size_t o = ((size_t)b*T_STEPS + trow)*MST + n;
      out[o] = out[o] + bias + C[r];
    }
  }
}

// ===========================================================================
// Fallback path (round-1 kernels) — used only if ws_size < WS_NEED.
// ===========================================================================
#define NHH (3*128*512)
#define NIH (3*32*512)
#define NFC (8*16*64)

__global__ __launch_bounds__(256) void prep_kernel(
    const float* __restrict__ W_ih, const float* __restrict__ W_hh,
    const float* __restrict__ fc_W, uint2* __restrict__ whh_p,
    uint2* __restrict__ wih_p, uint2* __restrict__ wfc_p){
  int idx = blockIdx.x*256 + threadIdx.x;
  if (idx < NHH){
    int g = idx >> 16, rem = idx & 65535, k4 = rem >> 9, jj = rem & 511;
    const float* src = W_hh + (g*512 + jj)*512 + k4*4;
    whh_p[idx] = make_uint2(packh2(src[0],src[1]), packh2(src[2],src[3]));
  } else if (idx < NHH + NIH){
    int t = idx - NHH;
    int g = t >> 14, rem = t & 16383, k4 = rem >> 9, jj = rem & 511;
    const float* src = W_ih + (g*512 + jj)*128 + k4*4;
    wih_p[t] = make_uint2(packh2(src[0],src[1]), packh2(src[2],src[3]));
  } else {
    int t = idx - NHH - NIH;
    int ss = t >> 10, rem = t & 1023, k4 = rem >> 6, i = rem & 63;
    const float* src = fc_W + i*512 + ss*64 + k4*4;
    wfc_p[t] = make_uint2(packh2(src[0],src[1]), packh2(src[2],src[3]));
  }
}

__global__ __launch_bounds__(512) void gru_kernel(
    const float* __restrict__ Y, const float* __restrict__ b_ih,
    const float* __restrict__ b_hh, const float* __restrict__ fc_b,
    const uint2* __restrict__ WIH, const uint2* __restrict__ WHH,
    const uint2* __restrict__ WFC, float* __restrict__ out){
  int b = blockIdx.x, j = threadIdx.x;
  int ss = j >> 6, ii = j & 63;
  __shared__ u32 inp2[64];
  __shared__ float xp_lds[64];
  __shared__ u32 hbuf2[256];
  __shared__ float fcred[8][64];
  float br  = b_ih[j]      + b_hh[j];
  float bz  = b_ih[512+j]  + b_hh[512+j];
  float bxn = b_ih[1024+j];
  float bhn = b_hh[1024+j];
  float fb  = (j<64)? fc_b[j] : 0.f;
  float hreg = 0.f;
  if (j < 256) hbuf2[j] = 0u;
  const float* yb = Y   + (size_t)b*1024*64;
  float*       ob = out + (size_t)b*1024*64;
  for (int t=0;t<1024;t++){
    const float* yrow = yb + t*64;
    float*       orow = ob + t*64;
    if (j < 64){
      xp_lds[j] = orow[j];
      if (j < 32){
        float2 v = *(const float2*)(yrow + 2*j);
        inp2[j] = packh2(v.x, v.y);
      } else {
        float2 v = *(const float2*)(orow + 2*(j-32));
        inp2[j] = packh2(v.x, v.y);
      }
    }
    __syncthreads();
    float sr=br, sz=bz, sxn=bxn, shn=bhn;
    #pragma unroll 8
    for (int m=0;m<32;m++){
      uint2 wr = WIH[(m   )*512 + j];
      uint2 wz = WIH[(32+m)*512 + j];
      uint2 wn = WIH[(64+m)*512 + j];
      u32 x0 = inp2[2*m], x1 = inp2[2*m+1];
      sr  = dot2f(wr.x,x0,sr );  sr  = dot2f(wr.y,x1,sr );
      sz  = dot2f(wz.x,x0,sz );  sz  = dot2f(wz.y,x1,sz );
      sxn = dot2f(wn.x,x0,sxn);  sxn = dot2f(wn.y,x1,sxn);
    }
    #pragma unroll 8
    for (int m=0;m<128;m++){
      uint2 wr = WHH[(m     )*512 + j];
      uint2 wz = WHH[(128+m)*512 + j];
      uint2 wn = WHH[(256+m)*512 + j];
      u32 h0 = hbuf2[2*m], h1 = hbuf2[2*m+1];
      sr  = dot2f(wr.x,h0,sr );  sr  = dot2f(wr.y,h1,sr );
      sz  = dot2f(wz.x,h0,sz );  sz  = dot2f(wz.y,h1,sz );
      shn = dot2f(wn.x,h0,shn);  shn = dot2f(wn.y,h1,shn);
    }
    float r  = sigm_slow(sr);
    float zg = sigm_slow(sz);
    float ng = tanhf(sxn + r*shn);
    float hnew = (1.f - zg)*ng + zg*hreg;
    hreg = hnew;
    __syncthreads();
    ((u16*)hbuf2)[j] = f16b(hnew);
    __syncthreads();
    float p = 0.f;
    #pragma unroll
    for (int k4=0;k4<16;k4++){
      uint2 w2 = WFC[(ss*16 + k4)*64 + ii];
      u32 h0 = hbuf2[ss*32 + 2*k4], h1 = hbuf2[ss*32 + 2*k4 + 1];
      p = dot2f(w2.x,h0,p);  p = dot2f(w2.y,h1,p);
    }
    fcred[ss][ii] = p;
    __syncthreads();
    if (j < 64){
      float dx = fb + xp_lds[j];
      #pragma unroll
      for (int q=0;q<8;q++) dx += fcred[q][j];
      orow[j] = dx;
    }
  }
}

extern "C" void kernel_launch(void* const* d_in, const int* in_sizes, int n_in,
                              void* d_out, int out_size, void* d_ws, size_t ws_size,
                              hipStream_t stream){
  (void)in_sizes; (void)n_in; (void)out_size;
  const float* Y   = (const float*)d_in[0];
  const float* x0  = (const float*)d_in[1];
  const float* F   = (const float*)d_in[2];
  const float* Wih = (const float*)d_in[3];
  const float* Whh = (const float*)d_in[4];
  const float* bih = (const float*)d_in[5];
  const float* bhh = (const float*)d_in[6];
  const float* fcW = (const float*)d_in[7];
  const float* fcb = (const float*)d_in[8];
  float* out = (float*)d_out;

  if (ws_size >= (size_t)WS_NEED){
    char* ws = (char*)d_ws;
    prep2_kernel <<<3969, 256, 0, stream>>>(Wih, Whh, fcW, ws);
    xprior_kernel<<<  64,  64, 0, stream>>>(F, x0, out);
    gru_pers3    <<< 128, 128, 0, stream>>>(Y, out, bih, bhh, ws);
    fc_kernel    <<<2048, 256, 0, stream>>>(fcb, ws, out);
  } else {
    uint2* whh_p = (uint2*)d_ws;
    uint2* wih_p = (uint2*)((char*)d_ws + 1572864);
    uint2* wfc_p = (uint2*)((char*)d_ws + 1966080);
    prep_kernel  <<<992, 256, 0, stream>>>(Wih, Whh, fcW, whh_p, wih_p, wfc_p);
    xprior_kernel<<< 64,  64, 0, stream>>>(F, x0, out);
    gru_kernel   <<< 64, 512, 0, stream>>>(Y, bih, bhh, fcb, wih_p, whh_p, wfc_p, out);
  }
}

// Round 12
// 3294.983 us; speedup vs baseline: 1.0243x; 1.0243x over previous
//
#include <hip/hip_runtime.h>

typedef unsigned int u32;
typedef unsigned short u16;
typedef _Float16 half8 __attribute__((ext_vector_type(8)));
typedef float f32x4 __attribute__((ext_vector_type(4)));
typedef _Float16 h2t __attribute__((ext_vector_type(2)));

union H2U { u32 u; h2t h; u16 s[2]; };
union U128 { uint4 u; half8 h; };

#if defined(__has_builtin)
#if __has_builtin(__builtin_amdgcn_fdot2)
#define HAS_FDOT2 1
#endif
#endif

__device__ __forceinline__ float dot2f(u32 w, u32 x, float acc){
  H2U a, b; a.u = w; b.u = x;
#ifdef HAS_FDOT2
  return __builtin_amdgcn_fdot2(a.h, b.h, acc, false);
#else
  return acc + (float)a.h.x * (float)b.h.x + (float)a.h.y * (float)b.h.y;
#endif
}
__device__ __forceinline__ u32 packh2(float a, float b){
  H2U u; u.h.x = (_Float16)a; u.h.y = (_Float16)b; return u.u;
}
__device__ __forceinline__ u16 f16b(float x){
  union { _Float16 h; u16 u; } c; c.h = (_Float16)x; return c.u;
}
__device__ __forceinline__ float rcpf(float x){ return __builtin_amdgcn_rcpf(x); }
__device__ __forceinline__ float sigm(float x){ return rcpf(1.0f + __expf(-x)); }
__device__ __forceinline__ float sigm_slow(float x){ return 1.0f/(1.0f + __expf(-x)); }
__device__ __forceinline__ float tanh_f(float x){
  return fmaf(-2.0f, rcpf(1.0f + __expf(2.0f*x)), 1.0f);
}
__device__ __forceinline__ half8 pack8(float4 u, float4 v){
  half8 r;
  r[0]=(_Float16)u.x; r[1]=(_Float16)u.y; r[2]=(_Float16)u.z; r[3]=(_Float16)u.w;
  r[4]=(_Float16)v.x; r[5]=(_Float16)v.y; r[6]=(_Float16)v.z; r[7]=(_Float16)v.w;
  return r;
}

// Coherence-point access: device-scope sc0 sc1 everywhere — the only sync
// semantics proven on this HW (R4/R7/R11). Asm outputs early-clobber.
#define LDX4_SC(dst, base, off) \
  asm volatile("global_load_dwordx4 %0, %1, off offset:" #off " sc0 sc1" \
               : "=&v"(dst) : "v"(base) : "memory")
#define STX2_SC(base, v2) \
  asm volatile("global_store_dwordx2 %0, %1, off sc0 sc1" \
               :: "v"(base), "v"(v2) : "memory")
#define STDW_SC(base, val) \
  asm volatile("global_store_dword %0, %1, off sc0 sc1" \
               :: "v"(base), "v"(val) : "memory")
#define WAIT_VM0() asm volatile("s_waitcnt vmcnt(0)" ::: "memory")

#define T_STEPS 1024
#define NB 64
#define HID 512
#define G3 1536
#define NOBS 64
#define MST 64
#define KIN 128

// ---- ws layout (persistent path), bytes ----
#define OFF_WHHK 0
#define SZ_WHHK (G3*HID*2)                    // 1,572,864
#define OFF_WIHK (OFF_WHHK + SZ_WHHK)
#define SZ_WIHK (G3*KIN*2)                    //   393,216
#define OFF_FCK (OFF_WIHK + SZ_WIHK)
#define SZ_FCK (MST*HID*2)                    //    65,536
#define OFF_FLG (OFF_FCK + SZ_FCK)
#define SZ_FLG (4*32*4)                       //       512 (4 teams x 32 WG flags)
#define OFF_HFULL (OFF_FLG + 4096)
#define SZ_HFULL ((size_t)T_STEPS*NB*HID*2)   // 67,108,864  (h_full[t] = outs[t])
#define WS_NEED (OFF_HFULL + SZ_HFULL)

// ---------------------------------------------------------------------------
// prep2: f32->f16 weight conversion; zero flags with sc0 sc1 stores (the
// persistent kernel polls them via cache-bypass loads). Proven R4/R7.
// ---------------------------------------------------------------------------
__global__ __launch_bounds__(256) void prep2_kernel(
    const float* __restrict__ W_ih, const float* __restrict__ W_hh,
    const float* __restrict__ fc_W, char* __restrict__ ws){
  _Float16* whhk = (_Float16*)(ws + OFF_WHHK);
  _Float16* wihk = (_Float16*)(ws + OFF_WIHK);
  _Float16* fck  = (_Float16*)(ws + OFF_FCK);
  u32* flg       = (u32*)(ws + OFF_FLG);
  long idx = (long)blockIdx.x*256 + threadIdx.x;
  const long N1 = (long)G3*HID, N2 = (long)G3*KIN, N3 = (long)MST*HID;
  const long N4 = SZ_FLG/4;
  if (idx < N1) whhk[idx] = (_Float16)W_hh[idx];
  else if (idx < N1+N2) wihk[idx-N1] = (_Float16)W_ih[idx-N1];
  else if (idx < N1+N2+N3) fck[idx-N1-N2] = (_Float16)fc_W[idx-N1-N2];
  else if (idx < N1+N2+N3+N4) { u32* p = flg + (idx-N1-N2-N3); u32 z = 0; STDW_SC(p, z); }
}

// ---------------------------------------------------------------------------
// X_prior: one WG (1 wave) per batch; F row-resident in VGPRs.
// Writes X_prior into d_out (fc kernel later adds dX in place).
// ---------------------------------------------------------------------------
__global__ __launch_bounds__(64) void xprior_kernel(
    const float* __restrict__ F, const float* __restrict__ x0,
    float* __restrict__ out){
  int b = blockIdx.x, i = threadIdx.x;
  __shared__ float xb[2][64];
  float f[64];
  #pragma unroll
  for (int j=0;j<64;j++) f[j] = F[i*64+j];
  xb[0][i] = x0[b*64+i];
  __syncthreads();
  float* o = out + (size_t)b*1024*64;
  for (int t=0;t<1024;t++){
    int cur = t & 1;
    float a0=0.f,a1=0.f,a2=0.f,a3=0.f;
    #pragma unroll
    for (int j=0;j<64;j+=4){
      a0 = fmaf(f[j+0], xb[cur][j+0], a0);
      a1 = fmaf(f[j+1], xb[cur][j+1], a1);
      a2 = fmaf(f[j+2], xb[cur][j+2], a2);
      a3 = fmaf(f[j+3], xb[cur][j+3], a3);
    }
    float a = (a0+a1)+(a2+a3);
    o[t*64+i] = a;
    xb[cur^1][i] = a;
    __syncthreads();
  }
}

// ---------------------------------------------------------------------------
// Persistent GRU v3.3 — R4/R7/R11 flag protocol; ONE change vs R11:
// MFMA operand roles swapped: D = mfma(A=W_frag, B=h_frag). The 16x16x32
// A and B fragment layouts are symmetric (row/col = lane&15, k = lk*8+i),
// so ALL existing register contents (weight frags, h loads, input loads)
// are reused unchanged — only the output orientation flips to D[n][b]:
// lane (lr,lk) now holds 4 outputs for (batch=lr, j = m*16+lk*4+{0..3}),
// i.e. 4 CONSECUTIVE columns of one batch. The publish therefore becomes
// ONE coalesced 8-byte dwordx2 per lane (lanes lk=0..3 form contiguous
// 32B per batch row): 16x32B transactions/WG instead of 256x2B scattered
// shorts — attacking the store-ack serialization in the producer tail.
// Protocol (stores -> vmcnt(0) ack -> flag), consumer loads, h_full
// layout, fc kernel: byte-identical to the proven versions.
// part[] double-buffered by t&1 (proof: wave1's part-write@t+2 requires
// passing syncthreads(t+1), which requires wave0 past its part-read@t).
// ---------------------------------------------------------------------------
__global__ __launch_bounds__(128, 1) void gru_pers3(
    const float* __restrict__ Y, const float* __restrict__ Xp,
    const float* __restrict__ b_ih, const float* __restrict__ b_hh,
    char* __restrict__ ws){
  const _Float16* whhk = (const _Float16*)(ws + OFF_WHHK);
  const _Float16* wihk = (const _Float16*)(ws + OFF_WIHK);
  u32* flags           = (u32*)(ws + OFF_FLG);
  _Float16* h_full     = (_Float16*)(ws + OFF_HFULL);

  const int blk = blockIdx.x;
  const int g = blk >> 5;          // team 0..3
  const int m = blk & 31;          // j-tile 0..31
  const int tid = threadIdx.x;
  const int wv = tid >> 6;         // K-half 0..1
  const int lane = tid & 63;
  const int lr = lane & 15, lk = lane >> 4;
  const int j = m*16 + lr;         // weight row loaded by this lane (A-op row)

  // Persistent W fragments (now used as the MFMA A-operand; same register
  // contents as the proven B-operand loads): 30 x half8 = 120 VGPRs.
  half8 BhR[8], BhZ[8], BhN[8], BxR[2], BxZ[2], BxN[2];
  #pragma unroll
  for (int c=0;c<8;c++){
    BhR[c] = *(const half8*)(whhk + ((size_t)(       j))*HID + wv*256 + c*32 + lk*8);
    BhZ[c] = *(const half8*)(whhk + ((size_t)(512  + j))*HID + wv*256 + c*32 + lk*8);
    BhN[c] = *(const half8*)(whhk + ((size_t)(1024 + j))*HID + wv*256 + c*32 + lk*8);
  }
  #pragma unroll
  for (int c=0;c<2;c++){
    BxR[c] = *(const half8*)(wihk + ((size_t)(       j))*KIN + wv*64 + c*32 + lk*8);
    BxZ[c] = *(const half8*)(wihk + ((size_t)(512  + j))*KIN + wv*64 + c*32 + lk*8);
    BxN[c] = *(const half8*)(wihk + ((size_t)(1024 + j))*KIN + wv*64 + c*32 + lk*8);
  }

  // Gate biases for the swapped output orientation: lane (lr,lk) owns
  // D rows n = m*16 + lk*4 + r (r=0..3), col b = g*16 + lr.
  const int j4 = m*16 + lk*4;
  float bRv[4], bZv[4], bNXv[4], bNHv[4];
  #pragma unroll
  for (int r=0;r<4;r++){
    bRv[r]  = b_ih[j4+r]      + b_hh[j4+r];
    bZv[r]  = b_ih[512+j4+r]  + b_hh[512+j4+r];
    bNXv[r] = b_ih[1024+j4+r];
    bNHv[r] = b_hh[1024+j4+r];
  }

  // B-operand input rows: wave0 streams Y (k 0..63), wave1 streams Xp
  // (k 64..127); lane col lr = batch within team (unchanged loads).
  const float* Arow = (wv==0 ? Y : Xp) + ((size_t)(g*16 + lr))*T_STEPS*64;

  u32* flg = flags + g*32;
  u32* myflag   = flg + m;
  // Poll only the 16 producers of this wave's K-half columns (R11).
  u32* pollflag = flg + wv*16 + (lane & 15);

  float hold[4] = {0.f, 0.f, 0.f, 0.f};   // h[b=g*16+lr][j4+r]
  __shared__ f32x4 part[2][4][64];        // double-buffered by t&1

  for (int t=0; t<T_STEPS; t++){
    const int s = t & 1;

    // 1) prefetch this wave's input chunk (plain cached loads)
    const float* asrc = Arow + (size_t)t*64;
    float4 i0 = *(const float4*)(asrc + lk*8);
    float4 i1 = *(const float4*)(asrc + lk*8 + 4);
    float4 i2 = *(const float4*)(asrc + 32 + lk*8);
    float4 i3 = *(const float4*)(asrc + 32 + lk*8 + 4);

    // 2) poll: the 16 flags this wave depends on (skip at t=0)
    if (t > 0){
      u32 v;
      for(;;){
        asm volatile("global_load_dword %0, %1, off sc0 sc1\n\ts_waitcnt vmcnt(0)"
                     : "=&v"(v) : "v"(pollflag) : "memory");
        if (__all((int)(v >= (u32)t))) break;
      }
    }

    // 3) issue h_t B-frag loads for this wave's K-half (cache-bypass;
    //    identical addresses/registers to the proven consumer loads)
    uint4 ah[8];
    if (t > 0){
      const _Float16* hb = h_full + ((size_t)(t-1)*NB + g*16 + lr)*HID + wv*256 + lk*8;
      LDX4_SC(ah[0], hb,   0); LDX4_SC(ah[1], hb,  64);
      LDX4_SC(ah[2], hb, 128); LDX4_SC(ah[3], hb, 192);
      LDX4_SC(ah[4], hb, 256); LDX4_SC(ah[5], hb, 320);
      LDX4_SC(ah[6], hb, 384); LDX4_SC(ah[7], hb, 448);
    }

    // 4a) x-projection MFMAs (swapped roles: A=W, B=input) overlap h loads
    f32x4 aR={0,0,0,0}, aZ={0,0,0,0}, aNH={0,0,0,0}, aNX={0,0,0,0};
    {
      half8 A0 = pack8(i0,i1), A1 = pack8(i2,i3);
      aR  = __builtin_amdgcn_mfma_f32_16x16x32_f16(BxR[0], A0, aR, 0,0,0);
      aZ  = __builtin_amdgcn_mfma_f32_16x16x32_f16(BxZ[0], A0, aZ, 0,0,0);
      aNX = __builtin_amdgcn_mfma_f32_16x16x32_f16(BxN[0], A0, aNX,0,0,0);
      aR  = __builtin_amdgcn_mfma_f32_16x16x32_f16(BxR[1], A1, aR, 0,0,0);
      aZ  = __builtin_amdgcn_mfma_f32_16x16x32_f16(BxZ[1], A1, aZ, 0,0,0);
      aNX = __builtin_amdgcn_mfma_f32_16x16x32_f16(BxN[1], A1, aNX,0,0,0);
    }

    // 4b) drain h loads; sched_barrier stops hh-MFMA hoisting past the wait
    WAIT_VM0();
    __builtin_amdgcn_sched_barrier(0);

    // 4c) hh MFMAs (swapped roles: A=W, B=h)
    if (t > 0){
      #pragma unroll
      for (int c=0;c<8;c++){
        U128 u; u.u = ah[c];
        half8 B = u.h;
        aR  = __builtin_amdgcn_mfma_f32_16x16x32_f16(BhR[c], B, aR, 0,0,0);
        aZ  = __builtin_amdgcn_mfma_f32_16x16x32_f16(BhZ[c], B, aZ, 0,0,0);
        aNH = __builtin_amdgcn_mfma_f32_16x16x32_f16(BhN[c], B, aNH,0,0,0);
      }
    }

    // 5) cross-wave K-reduction via LDS (double-buffered; proof in header)
    if (wv == 1){
      part[s][0][lane] = aR;  part[s][1][lane] = aZ;
      part[s][2][lane] = aNH; part[s][3][lane] = aNX;
    }
    __syncthreads();

    if (wv == 0){
      aR  += part[s][0][lane]; aZ  += part[s][1][lane];
      aNH += part[s][2][lane]; aNX += part[s][3][lane];
      // 6) gates: lane owns (batch=g*16+lr, cols j4+{0..3})
      float hn[4];
      #pragma unroll
      for (int r=0;r<4;r++){
        float rg = sigm(aR[r] + bRv[r]);
        float zg = sigm(aZ[r] + bZv[r]);
        float ng = tanh_f(aNX[r] + bNXv[r] + rg*(aNH[r] + bNHv[r]));
        hn[r] = (1.f - zg)*ng + zg*hold[r];
        hold[r] = hn[r];
      }
      // 7) publish h_{t+1} into h_full[t]: ONE coalesced dwordx2 per lane
      //    (4 consecutive j for batch lr) -> vmcnt(0) ack -> flag.
      _Float16* hw = h_full + ((size_t)t*NB + g*16 + lr)*HID + j4;
      uint2 qq = make_uint2(packh2(hn[0], hn[1]), packh2(hn[2], hn[3]));
      STX2_SC(hw, qq);
      WAIT_VM0();
      if (lane == 0){
        u32 tv = (u32)(t+1);
        STDW_SC(myflag, tv);
      }
    }
  }
}

// ---------------------------------------------------------------------------
// Deferred fc: out = X_prior(d_out) + h_full @ fcW^T + fc_b. MFMA, parallel.
// (h_full written with sc0sc1 at the coherence point; kernel-boundary
// acquire makes fc's plain loads coherent — validated R4/R7/R11.)
// ---------------------------------------------------------------------------
__global__ __launch_bounds__(256) void fc_kernel(
    const float* __restrict__ fc_b, const char* __restrict__ ws,
    float* __restrict__ out){
  const _Float16* fck    = (const _Float16*)(ws + OFF_FCK);
  const _Float16* h_full = (const _Float16*)(ws + OFF_HFULL);
  int blk = blockIdx.x;
  int b  = blk >> 5;
  int t0 = (blk & 31) * 32;
  int tid = threadIdx.x, wv = tid >> 6, lane = tid & 63;
  int lr = lane & 15, lk = lane >> 4;
  int n = wv*16 + lr;
  half8 Bf[16];
  #pragma unroll
  for (int c=0;c<16;c++)
    Bf[c] = *(const half8*)(fck + (size_t)n*HID + c*32 + lk*8);
  float bias = fc_b[n];
  #pragma unroll
  for (int mt=0;mt<2;mt++){
    f32x4 C = {0.f,0.f,0.f,0.f};
    #pragma unroll
    for (int c=0;c<16;c++){
      half8 A = *(const half8*)(h_full + ((size_t)(t0+mt*16+lr)*NB + b)*HID + c*32 + lk*8);
      C = __builtin_amdgcn_mfma_f32_16x16x32_f16(A, Bf[c], C, 0,0,0);
    }
    #pragma unroll
    for (int r=0;r<4;r++){
      int trow = t0 + mt*16 + lk*4 + r;
      size_t o = ((size_t)b*T_STEPS + trow)*MST + n;
      out[o] = out[o] + bias + C[r];
    }
  }
}

// ===========================================================================
// Fallback path (round-1 kernels) — used only if ws_size < WS_NEED.
// ===========================================================================
#define NHH (3*128*512)
#define NIH (3*32*512)
#define NFC (8*16*64)

__global__ __launch_bounds__(256) void prep_kernel(
    const float* __restrict__ W_ih, const float* __restrict__ W_hh,
    const float* __restrict__ fc_W, uint2* __restrict__ whh_p,
    uint2* __restrict__ wih_p, uint2* __restrict__ wfc_p){
  int idx = blockIdx.x*256 + threadIdx.x;
  if (idx < NHH){
    int g = idx >> 16, rem = idx & 65535, k4 = rem >> 9, jj = rem & 511;
    const float* src = W_hh + (g*512 + jj)*512 + k4*4;
    whh_p[idx] = make_uint2(packh2(src[0],src[1]), packh2(src[2],src[3]));
  } else if (idx < NHH + NIH){
    int t = idx - NHH;
    int g = t >> 14, rem = t & 16383, k4 = rem >> 9, jj = rem & 511;
    const float* src = W_ih + (g*512 + jj)*128 + k4*4;
    wih_p[t] = make_uint2(packh2(src[0],src[1]), packh2(src[2],src[3]));
  } else {
    int t = idx - NHH - NIH;
    int ss = t >> 10, rem = t & 1023, k4 = rem >> 6, i = rem & 63;
    const float* src = fc_W + i*512 + ss*64 + k4*4;
    wfc_p[t] = make_uint2(packh2(src[0],src[1]), packh2(src[2],src[3]));
  }
}

__global__ __launch_bounds__(512) void gru_kernel(
    const float* __restrict__ Y, const float* __restrict__ b_ih,
    const float* __restrict__ b_hh, const float* __restrict__ fc_b,
    const uint2* __restrict__ WIH, const uint2* __restrict__ WHH,
    const uint2* __restrict__ WFC, float* __restrict__ out){
  int b = blockIdx.x, j = threadIdx.x;
  int ss = j >> 6, ii = j & 63;
  __shared__ u32 inp2[64];
  __shared__ float xp_lds[64];
  __shared__ u32 hbuf2[256];
  __shared__ float fcred[8][64];
  float br  = b_ih[j]      + b_hh[j];
  float bz  = b_ih[512+j]  + b_hh[512+j];
  float bxn = b_ih[1024+j];
  float bhn = b_hh[1024+j];
  float fb  = (j<64)? fc_b[j] : 0.f;
  float hreg = 0.f;
  if (j < 256) hbuf2[j] = 0u;
  const float* yb = Y   + (size_t)b*1024*64;
  float*       ob = out + (size_t)b*1024*64;
  for (int t=0;t<1024;t++){
    const float* yrow = yb + t*64;
    float*       orow = ob + t*64;
    if (j < 64){
      xp_lds[j] = orow[j];
      if (j < 32){
        float2 v = *(const float2*)(yrow + 2*j);
        inp2[j] = packh2(v.x, v.y);
      } else {
        float2 v = *(const float2*)(orow + 2*(j-32));
        inp2[j] = packh2(v.x, v.y);
      }
    }
    __syncthreads();
    float sr=br, sz=bz, sxn=bxn, shn=bhn;
    #pragma unroll 8
    for (int m=0;m<32;m++){
      uint2 wr = WIH[(m   )*512 + j];
      uint2 wz = WIH[(32+m)*512 + j];
      uint2 wn = WIH[(64+m)*512 + j];
      u32 x0 = inp2[2*m], x1 = inp2[2*m+1];
      sr  = dot2f(wr.x,x0,sr );  sr  = dot2f(wr.y,x1,sr );
      sz  = dot2f(wz.x,x0,sz );  sz  = dot2f(wz.y,x1,sz );
      sxn = dot2f(wn.x,x0,sxn);  sxn = dot2f(wn.y,x1,sxn);
    }
    #pragma unroll 8
    for (int m=0;m<128;m++){
      uint2 wr = WHH[(m     )*512 + j];
      uint2 wz = WHH[(128+m)*512 + j];
      uint2 wn = WHH[(256+m)*512 + j];
      u32 h0 = hbuf2[2*m], h1 = hbuf2[2*m+1];
      sr  = dot2f(wr.x,h0,sr );  sr  = dot2f(wr.y,h1,sr );
      sz  = dot2f(wz.x,h0,sz );  sz  = dot2f(wz.y,h1,sz );
      shn = dot2f(wn.x,h0,shn);  shn = dot2f(wn.y,h1,shn);
    }
    float r  = sigm_slow(sr);
    float zg = sigm_slow(sz);
    float ng = tanhf(sxn + r*shn);
    float hnew = (1.f - zg)*ng + zg*hreg;
    hreg = hnew;
    __syncthreads();
    ((u16*)hbuf2)[j] = f16b(hnew);
    __syncthreads();
    float p = 0.f;
    #pragma unroll
    for (int k4=0;k4<16;k4++){
      uint2 w2 = WFC[(ss*16 + k4)*64 + ii];
      u32 h0 = hbuf2[ss*32 + 2*k4], h1 = hbuf2[ss*32 + 2*k4 + 1];
      p = dot2f(w2.x,h0,p);  p = dot2f(w2.y,h1,p);
    }
    fcred[ss][ii] = p;
    __syncthreads();
    if (j < 64){
      float dx = fb + xp_lds[j];
      #pragma unroll
      for (int q=0;q<8;q++) dx += fcred[q][j];
      orow[j] = dx;
    }
  }
}

extern "C" void kernel_launch(void* const* d_in, const int* in_sizes, int n_in,
                              void* d_out, int out_size, void* d_ws, size_t ws_size,
                              hipStream_t stream){
  (void)in_sizes; (void)n_in; (void)out_size;
  const float* Y   = (const float*)d_in[0];
  const float* x0  = (const float*)d_in[1];
  const float* F   = (const float*)d_in[2];
  const float* Wih = (const float*)d_in[3];
  const float* Whh = (const float*)d_in[4];
  const float* bih = (const float*)d_in[5];
  const float* bhh = (const float*)d_in[6];
  const float* fcW = (const float*)d_in[7];
  const float* fcb = (const float*)d_in[8];
  float* out = (float*)d_out;

  if (ws_size >= (size_t)WS_NEED){
    char* ws = (char*)d_ws;
    prep2_kernel <<<3969, 256, 0, stream>>>(Wih, Whh, fcW, ws);
    xprior_kernel<<<  64,  64, 0, stream>>>(F, x0, out);
    gru_pers3    <<< 128, 128, 0, stream>>>(Y, out, bih, bhh, ws);
    fc_kernel    <<<2048, 256, 0, stream>>>(fcb, ws, out);
  } else {
    uint2* whh_p = (uint2*)d_ws;
    uint2* wih_p = (uint2*)((char*)d_ws + 1572864);
    uint2* wfc_p = (uint2*)((char*)d_ws + 1966080);
    prep_kernel  <<<992, 256, 0, stream>>>(Wih, Whh, fcW, whh_p, wih_p, wfc_p);
    xprior_kernel<<< 64,  64, 0, stream>>>(F, x0, out);
    gru_kernel   <<< 64, 512, 0, stream>>>(Y, bih, bhh, fcb, wih_p, whh_p, wfc_p, out);
  }
}

// Round 13
// 3068.558 us; speedup vs baseline: 1.0999x; 1.0738x over previous
//
#include <hip/hip_runtime.h>

typedef unsigned int u32;
typedef unsigned short u16;
typedef _Float16 half8 __attribute__((ext_vector_type(8)));
typedef float f32x4 __attribute__((ext_vector_type(4)));
typedef _Float16 h2t __attribute__((ext_vector_type(2)));

union H2U { u32 u; h2t h; u16 s[2]; };
union U128 { uint4 u; half8 h; };

#if defined(__has_builtin)
#if __has_builtin(__builtin_amdgcn_fdot2)
#define HAS_FDOT2 1
#endif
#endif

__device__ __forceinline__ float dot2f(u32 w, u32 x, float acc){
  H2U a, b; a.u = w; b.u = x;
#ifdef HAS_FDOT2
  return __builtin_amdgcn_fdot2(a.h, b.h, acc, false);
#else
  return acc + (float)a.h.x * (float)b.h.x + (float)a.h.y * (float)b.h.y;
#endif
}
__device__ __forceinline__ u32 packh2(float a, float b){
  H2U u; u.h.x = (_Float16)a; u.h.y = (_Float16)b; return u.u;
}
__device__ __forceinline__ u16 f16b(float x){
  union { _Float16 h; u16 u; } c; c.h = (_Float16)x; return c.u;
}
__device__ __forceinline__ float rcpf(float x){ return __builtin_amdgcn_rcpf(x); }
__device__ __forceinline__ float sigm(float x){ return rcpf(1.0f + __expf(-x)); }
__device__ __forceinline__ float sigm_slow(float x){ return 1.0f/(1.0f + __expf(-x)); }
__device__ __forceinline__ float tanh_f(float x){
  return fmaf(-2.0f, rcpf(1.0f + __expf(2.0f*x)), 1.0f);
}
__device__ __forceinline__ half8 pack8(float4 u, float4 v){
  half8 r;
  r[0]=(_Float16)u.x; r[1]=(_Float16)u.y; r[2]=(_Float16)u.z; r[3]=(_Float16)u.w;
  r[4]=(_Float16)v.x; r[5]=(_Float16)v.y; r[6]=(_Float16)v.z; r[7]=(_Float16)v.w;
  return r;
}

// Coherence-point access: device-scope sc0 sc1 everywhere — the only sync
// semantics proven on this HW (R4/R7/R11/R12). Asm outputs early-clobber.
#define LDX4_SC(dst, base, off) \
  asm volatile("global_load_dwordx4 %0, %1, off offset:" #off " sc0 sc1" \
               : "=&v"(dst) : "v"(base) : "memory")
#define STX2_SC(base, v2) \
  asm volatile("global_store_dwordx2 %0, %1, off sc0 sc1" \
               :: "v"(base), "v"(v2) : "memory")
#define STDW_SC(base, val) \
  asm volatile("global_store_dword %0, %1, off sc0 sc1" \
               :: "v"(base), "v"(val) : "memory")
#define WAIT_VM0() asm volatile("s_waitcnt vmcnt(0)" ::: "memory")

#define T_STEPS 1024
#define NB 64
#define HID 512
#define G3 1536
#define NOBS 64
#define MST 64
#define KIN 128

// ---- ws layout (persistent path), bytes ----
#define OFF_WHHK 0
#define SZ_WHHK (G3*HID*2)                    // 1,572,864
#define OFF_WIHK (OFF_WHHK + SZ_WHHK)
#define SZ_WIHK (G3*KIN*2)                    //   393,216
#define OFF_FCK (OFF_WIHK + SZ_WIHK)
#define SZ_FCK (MST*HID*2)                    //    65,536
#define OFF_FLG (OFF_FCK + SZ_FCK)
// R13: one 64B cache line per flag (stride 16 dwords) — kills IF same-line
// convoying from 256 waves' poll loops. 4 teams x 32 WGs x 64 B = 8 KB.
#define FLG_STRIDE 16
#define SZ_FLG (4*32*FLG_STRIDE*4)            //     8,192
#define OFF_HFULL (OFF_FLG + SZ_FLG + 4096)
#define SZ_HFULL ((size_t)T_STEPS*NB*HID*2)   // 67,108,864  (h_full[t] = outs[t])
#define WS_NEED (OFF_HFULL + SZ_HFULL)

// ---------------------------------------------------------------------------
// prep2: f32->f16 weight conversion; zero flags with sc0 sc1 stores (the
// persistent kernel polls them via cache-bypass loads). Proven R4/R7.
// ---------------------------------------------------------------------------
__global__ __launch_bounds__(256) void prep2_kernel(
    const float* __restrict__ W_ih, const float* __restrict__ W_hh,
    const float* __restrict__ fc_W, char* __restrict__ ws){
  _Float16* whhk = (_Float16*)(ws + OFF_WHHK);
  _Float16* wihk = (_Float16*)(ws + OFF_WIHK);
  _Float16* fck  = (_Float16*)(ws + OFF_FCK);
  u32* flg       = (u32*)(ws + OFF_FLG);
  long idx = (long)blockIdx.x*256 + threadIdx.x;
  const long N1 = (long)G3*HID, N2 = (long)G3*KIN, N3 = (long)MST*HID;
  const long N4 = SZ_FLG/4;
  if (idx < N1) whhk[idx] = (_Float16)W_hh[idx];
  else if (idx < N1+N2) wihk[idx-N1] = (_Float16)W_ih[idx-N1];
  else if (idx < N1+N2+N3) fck[idx-N1-N2] = (_Float16)fc_W[idx-N1-N2];
  else if (idx < N1+N2+N3+N4) { u32* p = flg + (idx-N1-N2-N3); u32 z = 0; STDW_SC(p, z); }
}

// ---------------------------------------------------------------------------
// X_prior: one WG (1 wave) per batch; F row-resident in VGPRs.
// Writes X_prior into d_out (fc kernel later adds dX in place).
// ---------------------------------------------------------------------------
__global__ __launch_bounds__(64) void xprior_kernel(
    const float* __restrict__ F, const float* __restrict__ x0,
    float* __restrict__ out){
  int b = blockIdx.x, i = threadIdx.x;
  __shared__ float xb[2][64];
  float f[64];
  #pragma unroll
  for (int j=0;j<64;j++) f[j] = F[i*64+j];
  xb[0][i] = x0[b*64+i];
  __syncthreads();
  float* o = out + (size_t)b*1024*64;
  for (int t=0;t<1024;t++){
    int cur = t & 1;
    float a0=0.f,a1=0.f,a2=0.f,a3=0.f;
    #pragma unroll
    for (int j=0;j<64;j+=4){
      a0 = fmaf(f[j+0], xb[cur][j+0], a0);
      a1 = fmaf(f[j+1], xb[cur][j+1], a1);
      a2 = fmaf(f[j+2], xb[cur][j+2], a2);
      a3 = fmaf(f[j+3], xb[cur][j+3], a3);
    }
    float a = (a0+a1)+(a2+a3);
    o[t*64+i] = a;
    xb[cur^1][i] = a;
    __syncthreads();
  }
}

// ---------------------------------------------------------------------------
// Persistent GRU v3.4 — R4/R7/R11/R12 flag protocol; ONE change vs R12:
// each WG flag lives in its own 64B cache line (FLG_STRIDE=16 dwords).
// Rationale: previously the 4 teams' 128 flags occupied 8 cache lines; the
// 256 waves' device-scope poll loops convoyed thousands of same-line
// requests at the IF slice, inflating every protocol RT. Now poll traffic
// spreads over 128 lines (~16 deep instead of ~256). Protocol semantics,
// stores, ack, poll predicate: byte-identical.
// MFMA operand roles as in R12 (D = mfma(A=W, B=h); publish is one
// coalesced dwordx2 per lane). part[] double-buffered by t&1 (proof:
// wave1's part-write@t+2 requires passing syncthreads(t+1), which requires
// wave0 past its part-read@t).
// ---------------------------------------------------------------------------
__global__ __launch_bounds__(128, 1) void gru_pers3(
    const float* __restrict__ Y, const float* __restrict__ Xp,
    const float* __restrict__ b_ih, const float* __restrict__ b_hh,
    char* __restrict__ ws){
  const _Float16* whhk = (const _Float16*)(ws + OFF_WHHK);
  const _Float16* wihk = (const _Float16*)(ws + OFF_WIHK);
  u32* flags           = (u32*)(ws + OFF_FLG);
  _Float16* h_full     = (_Float16*)(ws + OFF_HFULL);

  const int blk = blockIdx.x;
  const int g = blk >> 5;          // team 0..3
  const int m = blk & 31;          // j-tile 0..31
  const int tid = threadIdx.x;
  const int wv = tid >> 6;         // K-half 0..1
  const int lane = tid & 63;
  const int lr = lane & 15, lk = lane >> 4;
  const int j = m*16 + lr;         // weight row loaded by this lane (A-op row)

  // Persistent W fragments (MFMA A-operand): 30 x half8 = 120 VGPRs.
  half8 BhR[8], BhZ[8], BhN[8], BxR[2], BxZ[2], BxN[2];
  #pragma unroll
  for (int c=0;c<8;c++){
    BhR[c] = *(const half8*)(whhk + ((size_t)(       j))*HID + wv*256 + c*32 + lk*8);
    BhZ[c] = *(const half8*)(whhk + ((size_t)(512  + j))*HID + wv*256 + c*32 + lk*8);
    BhN[c] = *(const half8*)(whhk + ((size_t)(1024 + j))*HID + wv*256 + c*32 + lk*8);
  }
  #pragma unroll
  for (int c=0;c<2;c++){
    BxR[c] = *(const half8*)(wihk + ((size_t)(       j))*KIN + wv*64 + c*32 + lk*8);
    BxZ[c] = *(const half8*)(wihk + ((size_t)(512  + j))*KIN + wv*64 + c*32 + lk*8);
    BxN[c] = *(const half8*)(wihk + ((size_t)(1024 + j))*KIN + wv*64 + c*32 + lk*8);
  }

  // Gate biases (swapped output orientation, R12): lane (lr,lk) owns
  // D rows n = m*16 + lk*4 + r (r=0..3), col b = g*16 + lr.
  const int j4 = m*16 + lk*4;
  float bRv[4], bZv[4], bNXv[4], bNHv[4];
  #pragma unroll
  for (int r=0;r<4;r++){
    bRv[r]  = b_ih[j4+r]      + b_hh[j4+r];
    bZv[r]  = b_ih[512+j4+r]  + b_hh[512+j4+r];
    bNXv[r] = b_ih[1024+j4+r];
    bNHv[r] = b_hh[1024+j4+r];
  }

  // B-operand input rows: wave0 streams Y (k 0..63), wave1 streams Xp
  // (k 64..127); lane col lr = batch within team.
  const float* Arow = (wv==0 ? Y : Xp) + ((size_t)(g*16 + lr))*T_STEPS*64;

  u32* flg = flags + g*32*FLG_STRIDE;
  u32* myflag   = flg + m*FLG_STRIDE;
  // Poll only the 16 producers of this wave's K-half columns (R11),
  // each in its own cache line (R13).
  u32* pollflag = flg + (wv*16 + (lane & 15))*FLG_STRIDE;

  float hold[4] = {0.f, 0.f, 0.f, 0.f};   // h[b=g*16+lr][j4+r]
  __shared__ f32x4 part[2][4][64];        // double-buffered by t&1

  for (int t=0; t<T_STEPS; t++){
    const int s = t & 1;

    // 1) prefetch this wave's input chunk (plain cached loads)
    const float* asrc = Arow + (size_t)t*64;
    float4 i0 = *(const float4*)(asrc + lk*8);
    float4 i1 = *(const float4*)(asrc + lk*8 + 4);
    float4 i2 = *(const float4*)(asrc + 32 + lk*8);
    float4 i3 = *(const float4*)(asrc + 32 + lk*8 + 4);

    // 2) poll: the 16 flags this wave depends on (skip at t=0)
    if (t > 0){
      u32 v;
      for(;;){
        asm volatile("global_load_dword %0, %1, off sc0 sc1\n\ts_waitcnt vmcnt(0)"
                     : "=&v"(v) : "v"(pollflag) : "memory");
        if (__all((int)(v >= (u32)t))) break;
      }
    }

    // 3) issue h_t B-frag loads for this wave's K-half (cache-bypass)
    uint4 ah[8];
    if (t > 0){
      const _Float16* hb = h_full + ((size_t)(t-1)*NB + g*16 + lr)*HID + wv*256 + lk*8;
      LDX4_SC(ah[0], hb,   0); LDX4_SC(ah[1], hb,  64);
      LDX4_SC(ah[2], hb, 128); LDX4_SC(ah[3], hb, 192);
      LDX4_SC(ah[4], hb, 256); LDX4_SC(ah[5], hb, 320);
      LDX4_SC(ah[6], hb, 384); LDX4_SC(ah[7], hb, 448);
    }

    // 4a) x-projection MFMAs (A=W, B=input) overlap the h-load round trip
    f32x4 aR={0,0,0,0}, aZ={0,0,0,0}, aNH={0,0,0,0}, aNX={0,0,0,0};
    {
      half8 A0 = pack8(i0,i1), A1 = pack8(i2,i3);
      aR  = __builtin_amdgcn_mfma_f32_16x16x32_f16(BxR[0], A0, aR, 0,0,0);
      aZ  = __builtin_amdgcn_mfma_f32_16x16x32_f16(BxZ[0], A0, aZ, 0,0,0);
      aNX = __builtin_amdgcn_mfma_f32_16x16x32_f16(BxN[0], A0, aNX,0,0,0);
      aR  = __builtin_amdgcn_mfma_f32_16x16x32_f16(BxR[1], A1, aR, 0,0,0);
      aZ  = __builtin_amdgcn_mfma_f32_16x16x32_f16(BxZ[1], A1, aZ, 0,0,0);
      aNX = __builtin_amdgcn_mfma_f32_16x16x32_f16(BxN[1], A1, aNX,0,0,0);
    }

    // 4b) drain h loads; sched_barrier stops hh-MFMA hoisting past the wait
    WAIT_VM0();
    __builtin_amdgcn_sched_barrier(0);

    // 4c) hh MFMAs (A=W, B=h)
    if (t > 0){
      #pragma unroll
      for (int c=0;c<8;c++){
        U128 u; u.u = ah[c];
        half8 B = u.h;
        aR  = __builtin_amdgcn_mfma_f32_16x16x32_f16(BhR[c], B, aR, 0,0,0);
        aZ  = __builtin_amdgcn_mfma_f32_16x16x32_f16(BhZ[c], B, aZ, 0,0,0);
        aNH = __builtin_amdgcn_mfma_f32_16x16x32_f16(BhN[c], B, aNH,0,0,0);
      }
    }

    // 5) cross-wave K-reduction via LDS (double-buffered; proof in header)
    if (wv == 1){
      part[s][0][lane] = aR;  part[s][1][lane] = aZ;
      part[s][2][lane] = aNH; part[s][3][lane] = aNX;
    }
    __syncthreads();

    if (wv == 0){
      aR  += part[s][0][lane]; aZ  += part[s][1][lane];
      aNH += part[s][2][lane]; aNX += part[s][3][lane];
      // 6) gates: lane owns (batch=g*16+lr, cols j4+{0..3})
      float hn[4];
      #pragma unroll
      for (int r=0;r<4;r++){
        float rg = sigm(aR[r] + bRv[r]);
        float zg = sigm(aZ[r] + bZv[r]);
        float ng = tanh_f(aNX[r] + bNXv[r] + rg*(aNH[r] + bNHv[r]));
        hn[r] = (1.f - zg)*ng + zg*hold[r];
        hold[r] = hn[r];
      }
      // 7) publish h_{t+1} into h_full[t]: one coalesced dwordx2 per lane
      //    -> vmcnt(0) ack -> flag (proven producer protocol).
      _Float16* hw = h_full + ((size_t)t*NB + g*16 + lr)*HID + j4;
      uint2 qq = make_uint2(packh2(hn[0], hn[1]), packh2(hn[2], hn[3]));
      STX2_SC(hw, qq);
      WAIT_VM0();
      if (lane == 0){
        u32 tv = (u32)(t+1);
        STDW_SC(myflag, tv);
      }
    }
  }
}

// ---------------------------------------------------------------------------
// Deferred fc: out = X_prior(d_out) + h_full @ fcW^T + fc_b. MFMA, parallel.
// (h_full written with sc0sc1 at the coherence point; kernel-boundary
// acquire makes fc's plain loads coherent — validated R4/R7/R11/R12.)
// ---------------------------------------------------------------------------
__global__ __launch_bounds__(256) void fc_kernel(
    const float* __restrict__ fc_b, const char* __restrict__ ws,
    float* __restrict__ out){
  const _Float16* fck    = (const _Float16*)(ws + OFF_FCK);
  const _Float16* h_full = (const _Float16*)(ws + OFF_HFULL);
  int blk = blockIdx.x;
  int b  = blk >> 5;
  int t0 = (blk & 31) * 32;
  int tid = threadIdx.x, wv = tid >> 6, lane = tid & 63;
  int lr = lane & 15, lk = lane >> 4;
  int n = wv*16 + lr;
  half8 Bf[16];
  #pragma unroll
  for (int c=0;c<16;c++)
    Bf[c] = *(const half8*)(fck + (size_t)n*HID + c*32 + lk*8);
  float bias = fc_b[n];
  #pragma unroll
  for (int mt=0;mt<2;mt++){
    f32x4 C = {0.f,0.f,0.f,0.f};
    #pragma unroll
    for (int c=0;c<16;c++){
      half8 A = *(const half8*)(h_full + ((size_t)(t0+mt*16+lr)*NB + b)*HID + c*32 + lk*8);
      C = __builtin_amdgcn_mfma_f32_16x16x32_f16(A, Bf[c], C, 0,0,0);
    }
    #pragma unroll
    for (int r=0;r<4;r++){
      int trow = t0 + mt*16 + lk*4 + r;
      size_t o = ((size_t)b*T_STEPS + trow)*MST + n;
      out[o] = out[o] + bias + C[r];
    }
  }
}

// ===========================================================================
// Fallback path (round-1 kernels) — used only if ws_size < WS_NEED.
// ===========================================================================
#define NHH (3*128*512)
#define NIH (3*32*512)
#define NFC (8*16*64)

__global__ __launch_bounds__(256) void prep_kernel(
    const float* __restrict__ W_ih, const float* __restrict__ W_hh,
    const float* __restrict__ fc_W, uint2* __restrict__ whh_p,
    uint2* __restrict__ wih_p, uint2* __restrict__ wfc_p){
  int idx = blockIdx.x*256 + threadIdx.x;
  if (idx < NHH){
    int g = idx >> 16, rem = idx & 65535, k4 = rem >> 9, jj = rem & 511;
    const float* src = W_hh + (g*512 + jj)*512 + k4*4;
    whh_p[idx] = make_uint2(packh2(src[0],src[1]), packh2(src[2],src[3]));
  } else if (idx < NHH + NIH){
    int t = idx - NHH;
    int g = t >> 14, rem = t & 16383, k4 = rem >> 9, jj = rem & 511;
    const float* src = W_ih + (g*512 + jj)*128 + k4*4;
    wih_p[t] = make_uint2(packh2(src[0],src[1]), packh2(src[2],src[3]));
  } else {
    int t = idx - NHH - NIH;
    int ss = t >> 10, rem = t & 1023, k4 = rem >> 6, i = rem & 63;
    const float* src = fc_W + i*512 + ss*64 + k4*4;
    wfc_p[t] = make_uint2(packh2(src[0],src[1]), packh2(src[2],src[3]));
  }
}

__global__ __launch_bounds__(512) void gru_kernel(
    const float* __restrict__ Y, const float* __restrict__ b_ih,
    const float* __restrict__ b_hh, const float* __restrict__ fc_b,
    const uint2* __restrict__ WIH, const uint2* __restrict__ WHH,
    const uint2* __restrict__ WFC, float* __restrict__ out){
  int b = blockIdx.x, j = threadIdx.x;
  int ss = j >> 6, ii = j & 63;
  __shared__ u32 inp2[64];
  __shared__ float xp_lds[64];
  __shared__ u32 hbuf2[256];
  __shared__ float fcred[8][64];
  float br  = b_ih[j]      + b_hh[j];
  float bz  = b_ih[512+j]  + b_hh[512+j];
  float bxn = b_ih[1024+j];
  float bhn = b_hh[1024+j];
  float fb  = (j<64)? fc_b[j] : 0.f;
  float hreg = 0.f;
  if (j < 256) hbuf2[j] = 0u;
  const float* yb = Y   + (size_t)b*1024*64;
  float*       ob = out + (size_t)b*1024*64;
  for (int t=0;t<1024;t++){
    const float* yrow = yb + t*64;
    float*       orow = ob + t*64;
    if (j < 64){
      xp_lds[j] = orow[j];
      if (j < 32){
        float2 v = *(const float2*)(yrow + 2*j);
        inp2[j] = packh2(v.x, v.y);
      } else {
        float2 v = *(const float2*)(orow + 2*(j-32));
        inp2[j] = packh2(v.x, v.y);
      }
    }
    __syncthreads();
    float sr=br, sz=bz, sxn=bxn, shn=bhn;
    #pragma unroll 8
    for (int m=0;m<32;m++){
      uint2 wr = WIH[(m   )*512 + j];
      uint2 wz = WIH[(32+m)*512 + j];
      uint2 wn = WIH[(64+m)*512 + j];
      u32 x0 = inp2[2*m], x1 = inp2[2*m+1];
      sr  = dot2f(wr.x,x0,sr );  sr  = dot2f(wr.y,x1,sr );
      sz  = dot2f(wz.x,x0,sz );  sz  = dot2f(wz.y,x1,sz );
      sxn = dot2f(wn.x,x0,sxn);  sxn = dot2f(wn.y,x1,sxn);
    }
    #pragma unroll 8
    for (int m=0;m<128;m++){
      uint2 wr = WHH[(m     )*512 + j];
      uint2 wz = WHH[(128+m)*512 + j];
      uint2 wn = WHH[(256+m)*512 + j];
      u32 h0 = hbuf2[2*m], h1 = hbuf2[2*m+1];
      sr  = dot2f(wr.x,h0,sr );  sr  = dot2f(wr.y,h1,sr );
      sz  = dot2f(wz.x,h0,sz );  sz  = dot2f(wz.y,h1,sz );
      shn = dot2f(wn.x,h0,shn);  shn = dot2f(wn.y,h1,shn);
    }
    float r  = sigm_slow(sr);
    float zg = sigm_slow(sz);
    float ng = tanhf(sxn + r*shn);
    float hnew = (1.f - zg)*ng + zg*hreg;
    hreg = hnew;
    __syncthreads();
    ((u16*)hbuf2)[j] = f16b(hnew);
    __syncthreads();
    float p = 0.f;
    #pragma unroll
    for (int k4=0;k4<16;k4++){
      uint2 w2 = WFC[(ss*16 + k4)*64 + ii];
      u32 h0 = hbuf2[ss*32 + 2*k4], h1 = hbuf2[ss*32 + 2*k4 + 1];
      p = dot2f(w2.x,h0,p);  p = dot2f(w2.y,h1,p);
    }
    fcred[ss][ii] = p;
    __syncthreads();
    if (j < 64){
      float dx = fb + xp_lds[j];
      #pragma unroll
      for (int q=0;q<8;q++) dx += fcred[q][j];
      orow[j] = dx;
    }
  }
}

extern "C" void kernel_launch(void* const* d_in, const int* in_sizes, int n_in,
                              void* d_out, int out_size, void* d_ws, size_t ws_size,
                              hipStream_t stream){
  (void)in_sizes; (void)n_in; (void)out_size;
  const float* Y   = (const float*)d_in[0];
  const float* x0  = (const float*)d_in[1];
  const float* F   = (const float*)d_in[2];
  const float* Wih = (const float*)d_in[3];
  const float* Whh = (const float*)d_in[4];
  const float* bih = (const float*)d_in[5];
  const float* bhh = (const float*)d_in[6];
  const float* fcW = (const float*)d_in[7];
  const float* fcb = (const float*)d_in[8];
  float* out = (float*)d_out;

  if (ws_size >= (size_t)WS_NEED){
    char* ws = (char*)d_ws;
    prep2_kernel <<<3976, 256, 0, stream>>>(Wih, Whh, fcW, ws);
    xprior_kernel<<<  64,  64, 0, stream>>>(F, x0, out);
    gru_pers3    <<< 128, 128, 0, stream>>>(Y, out, bih, bhh, ws);
    fc_kernel    <<<2048, 256, 0, stream>>>(fcb, ws, out);
  } else {
    uint2* whh_p = (uint2*)d_ws;
    uint2* wih_p = (uint2*)((char*)d_ws + 1572864);
    uint2* wfc_p = (uint2*)((char*)d_ws + 1966080);
    prep_kernel  <<<992, 256, 0, stream>>>(Wih, Whh, fcW, whh_p, wih_p, wfc_p);
    xprior_kernel<<< 64,  64, 0, stream>>>(F, x0, out);
    gru_kernel   <<< 64, 512, 0, stream>>>(Y, bih, bhh, fcb, wih_p, whh_p, wfc_p, out);
  }
}